// Round 19
// baseline (156.996 us; speedup 1.0000x reference)
//
#include <hip/hip_runtime.h>

typedef float f32x4 __attribute__((ext_vector_type(4)));
typedef short s16x8 __attribute__((ext_vector_type(8)));
typedef unsigned short u16;
typedef unsigned int u32;

#define MFMA16 __builtin_amdgcn_mfma_f32_16x16x32_bf16
#define SCALE 0.17677669529663687f  // 32^-0.5
#define LOG2E 1.44269504088896f

__device__ __forceinline__ u16 f2b(float f) {
  union { float f; unsigned u; } x; x.f = f;
  unsigned r = x.u + 0x7fffu + ((x.u >> 16) & 1u);
  return (u16)(r >> 16);
}
__device__ __forceinline__ float b2f(u16 s) {
  union { unsigned u; float f; } x; x.u = ((unsigned)s) << 16;
  return x.f;
}
// pack two f32 -> u32 of two bf16 (low = a, high = b), TRUNCATE, 1 inst
__device__ __forceinline__ u32 pkt(float a, float b) {
  return __builtin_amdgcn_perm(__builtin_bit_cast(u32, b),
                               __builtin_bit_cast(u32, a), 0x07060302u);
}
__device__ __forceinline__ u32 bperm(int idx, u32 src) {
  return (u32)__builtin_amdgcn_ds_bpermute(idx, (int)src);
}
__device__ __forceinline__ s16x8 mk8(u32 a, u32 b, u32 c, u32 d) {
  union { u32 w[4]; s16x8 v; } u;
  u.w[0] = a; u.w[1] = b; u.w[2] = c; u.w[3] = d;
  return u.v;
}

// ---------------- weight transpose + bf16 cast: WT[j][d] = bf16(W[d][j]) ----
__global__ __launch_bounds__(256) void wtrans_kernel(
    const float* __restrict__ Wq, const float* __restrict__ Wk,
    const float* __restrict__ Wv, const float* __restrict__ Wo,
    u16* __restrict__ WqT, u16* __restrict__ WkT,
    u16* __restrict__ WvT, u16* __restrict__ WoT) {
  const float* src; u16* dst;
  switch (blockIdx.x) {
    case 0: src = Wq; dst = WqT; break;
    case 1: src = Wk; dst = WkT; break;
    case 2: src = Wv; dst = WvT; break;
    default: src = Wo; dst = WoT; break;
  }
  int j = blockIdx.y;
  int d = threadIdx.x;
  dst[j * 256 + d] = f2b(src[d * 256 + j]);
}

// ---------------- xq passthrough (output 1) --------------------------------
__global__ __launch_bounds__(256) void copyxq_kernel(const float* __restrict__ xq,
                                                     float* __restrict__ dst) {
  int i = blockIdx.x * 256 + threadIdx.x;
  dst[i] = xq[i];
}

// ---------------- QKV projection: bf16 MFMA GEMM ---------------------------
__global__ __launch_bounds__(256) void proj_kernel(
    const float* __restrict__ zq, const float* __restrict__ zk,
    const float* __restrict__ zv,
    const u16* __restrict__ WqT, const u16* __restrict__ WkT,
    const u16* __restrict__ WvT,
    u16* __restrict__ qb, u16* __restrict__ kb, u16* __restrict__ vT) {
  const int mat = blockIdx.z;
  const float* Z = (mat == 0) ? zq : (mat == 1) ? zk : zv;
  const u16* WT = (mat == 0) ? WqT : (mat == 1) ? WkT : WvT;
  const int n0 = blockIdx.x * 64;
  const int j0 = blockIdx.y * 64;
  const int tid = threadIdx.x;
  const int lane = tid & 63, wid = tid >> 6;
  const int l15 = lane & 15, lg = lane >> 4;
  const int wn = wid & 1, wj = wid >> 1;

  __shared__ u16 As[64][40];
  __shared__ u16 Bs[64][40];

  f32x4 acc[2][2];
  #pragma unroll
  for (int a = 0; a < 2; ++a)
    #pragma unroll
    for (int b = 0; b < 2; ++b) acc[a][b] = (f32x4){0.f, 0.f, 0.f, 0.f};

  for (int ks = 0; ks < 8; ++ks) {
    const int d0 = ks * 32;
    const int r = tid >> 2, cb = (tid & 3) * 8;
    const float* zsrc = &Z[(size_t)(n0 + r) * 256 + d0 + cb];
    s16x8 t;
    #pragma unroll
    for (int j = 0; j < 8; ++j) t[j] = (short)f2b(zsrc[j]);
    *(s16x8*)&As[r][cb] = t;
    *(s16x8*)&Bs[r][cb] = *(const s16x8*)&WT[(size_t)(j0 + r) * 256 + d0 + cb];
    __syncthreads();
    s16x8 a0 = *(const s16x8*)&As[wn * 32 + l15][lg * 8];
    s16x8 a1 = *(const s16x8*)&As[wn * 32 + 16 + l15][lg * 8];
    s16x8 b0 = *(const s16x8*)&Bs[wj * 32 + l15][lg * 8];
    s16x8 b1 = *(const s16x8*)&Bs[wj * 32 + 16 + l15][lg * 8];
    acc[0][0] = MFMA16(a0, b0, acc[0][0], 0, 0, 0);
    acc[0][1] = MFMA16(a0, b1, acc[0][1], 0, 0, 0);
    acc[1][0] = MFMA16(a1, b0, acc[1][0], 0, 0, 0);
    acc[1][1] = MFMA16(a1, b1, acc[1][1], 0, 0, 0);
    __syncthreads();
  }
  #pragma unroll
  for (int sn = 0; sn < 2; ++sn)
    #pragma unroll
    for (int sj = 0; sj < 2; ++sj)
      #pragma unroll
      for (int i = 0; i < 4; ++i) {
        int n = n0 + wn * 32 + sn * 16 + lg * 4 + i;
        int j = j0 + wj * 32 + sj * 16 + l15;
        float av = acc[sn][sj][i];
        if (mat == 0) av *= SCALE;
        u16 val = f2b(av);
        if (mat == 0) {
          qb[(size_t)n * 256 + j] = val;
        } else if (mat == 1) {
          kb[(size_t)n * 256 + j] = val;
        } else {
          int mm = n >> 10, nn = n & 1023;
          vT[((size_t)(mm * 256 + j)) * 1024 + nn] = val;
        }
      }
}

// ---------------- fused TE attention: 4-wave blocks, 64-key tiles ----------
// 1024 blocks x 256 thr (4 waves). Decode: m = bid&7 (XCD affinity),
// qblk = (bid>>3)&63, kz = bid>>9 (512-key slice, 8 tiles of 64).
// Wave wid owns keys wid*16..+15 of each 64-tile for dots/MLP; heads
// {2*wid, 2*wid+1} for PV. P_s [8h][16q][72] = 18432 B.
// launch_bounds (256,5): reg budget 102 >= 64 arch + 24 AGPR = 88, no
// spill, up to 5 blocks/CU (R18's (256,4) sat at 3 blocks = 37.6% occ).
__global__ __launch_bounds__(256, 5) void attn_kernel(
    const u16* __restrict__ qb, const u16* __restrict__ kb,
    const u16* __restrict__ vT,
    const float* __restrict__ xq, const float* __restrict__ xkv,
    const float* __restrict__ W1, const float* __restrict__ b1,
    const float* __restrict__ W2, const float* __restrict__ b2,
    u16* __restrict__ preP, float* __restrict__ Lb) {
  const int bid = blockIdx.x;
  const int m = bid & 7;                 // XCD affinity: batch per XCD
  const int q0 = ((bid >> 3) & 63) * 16;
  const int kz = bid >> 9;               // 0..1
  const int tid = threadIdx.x;
  const int lane = tid & 63;
  const int wid = tid >> 6;              // 0..3
  const int l15 = lane & 15;
  const int lg = lane >> 4;
  const int kk = wid * 16 + l15;         // key in 64-tile

  u16* myPre = preP + (size_t)kz * (8192 * 256);
  float* myL = Lb + (size_t)kz * (8192 * 8);

  __shared__ u16 P_s[8][16][72];  // 18432 B (row 144 B, 16B-aligned)

  // resident W1^T A-fragments, channel-permuted:
  // row r of block b holds channel c = 8*(r>>2) + 4*b + (r&3)
  s16x8 w1a[2];
  #pragma unroll
  for (int cblk = 0; cblk < 2; ++cblk) {
    const int c = 8 * (l15 >> 2) + 4 * cblk + (l15 & 3);
    #pragma unroll
    for (int j = 0; j < 8; ++j) {
      const int dim = lg * 8 + j;
      u16 v = 0;
      if (dim < 10) v = f2b(W1[dim * 32 + c]);
      else if (dim == 10) v = f2b(b1[c]);
      w1a[cblk][j] = (short)v;
    }
  }
  // resident W2^T A-fragment (pre-scaled by log2e):
  // A[row=h=l15 (<8)][K=c=lg*8+j] (identity c-order)
  s16x8 w2a;
  #pragma unroll
  for (int j = 0; j < 8; ++j) {
    const int c = lg * 8 + j;
    w2a[j] = (short)((l15 < 8) ? f2b(W2[c * 8 + l15] * LOG2E) : (u16)0);
  }
  // b2 (pre-scaled) as MFMA C-in: lane (l15,lg) C row = lg*4+i = head (lg<2)
  f32x4 b2v;
  #pragma unroll
  for (int i = 0; i < 4; ++i) b2v[i] = b2[(lg & 1) * 4 + i] * LOG2E;

  // bpermute index registers (byte-indexed: lane*4)
  const int idx10 = (l15 + 0) * 4;   // pull from lg'=0
  const int idx11 = (l15 + 16) * 4;  // lg'=1
  const int idx12 = (l15 + 32) * 4;  // lg'=2
  const int idx13 = (l15 + 48) * 4;  // lg'=3
  const u32 u1base = (lg == 1) ? 0x00003F80u : 0u;  // dims(10,11)=(1.0,0)
  const bool lglo = (lg < 2);

  s16x8 ones;
  #pragma unroll
  for (int j = 0; j < 8; ++j) ones[j] = (l15 == 0) ? (short)0x3F80 : (short)0;

  // hoisted Q A-fragments (kt-invariant): 8 x 16B
  s16x8 qfr[8];
  #pragma unroll
  for (int h = 0; h < 8; ++h)
    qfr[h] = *(const s16x8*)&qb[((size_t)(m * 1024 + q0 + l15)) * 256 + h * 32 + lg * 8];

  f32x4 acc_pv[2][2];   // [head hh][d half]
  f32x4 acc_sum[2];     // [head hh]
  #pragma unroll
  for (int hh = 0; hh < 2; ++hh) {
    acc_pv[hh][0] = (f32x4){0.f, 0.f, 0.f, 0.f};
    acc_pv[hh][1] = (f32x4){0.f, 0.f, 0.f, 0.f};
    acc_sum[hh] = (f32x4){0.f, 0.f, 0.f, 0.f};
  }
  const f32x4 Z4 = (f32x4){0.f, 0.f, 0.f, 0.f};

  for (int kt = 0; kt < 8; ++kt) {
    const int kg = kz * 512 + kt * 64;  // global key base of 64-tile
    const float2 xk2 = *(const float2*)&xkv[((size_t)(m * 1024 + kg + kk)) * 2];

    // ---- dots: 8 MFMA (per head), K frags from global (L2) ----
    u32 dpk[4][4];
    {
      f32x4 dacc[8];
      #pragma unroll
      for (int h = 0; h < 8; ++h) {
        const s16x8 b = *(const s16x8*)&kb[((size_t)(m * 1024 + kg + kk)) * 256 + h * 32 + lg * 8];
        dacc[h] = MFMA16(qfr[h], b, Z4, 0, 0, 0);
      }
      // lane (l15,lg) holds q=lg*4+i, key=l15: pack head-pairs to bf16
      #pragma unroll
      for (int i = 0; i < 4; ++i)
        #pragma unroll
        for (int j = 0; j < 4; ++j)
          dpk[i][j] = pkt(dacc[2 * j][i], dacc[2 * j + 1][i]);
    }

    // ---- 16 pair-groups: qg = one q x this wave's 16 keys ----
    #pragma unroll 8
    for (int qg = 0; qg < 16; ++qg) {
      const int isrc = qg & 3;
      const int idxq = (qg >> 2) == 0 ? idx10 : (qg >> 2) == 1 ? idx11
                     : (qg >> 2) == 2 ? idx12 : idx13;
      // pull q=qg's dot-pairs from lane (l15, qg>>2); own key stays l15
      const u32 p0 = bperm(idxq, dpk[isrc][0]);
      const u32 p1 = bperm(idxq, dpk[isrc][1]);
      const u32 p2 = bperm(idxq, dpk[isrc][2]);
      const u32 p3 = bperm(idxq, dpk[isrc][3]);
      // position diff (uniform xq load, per-lane xk)
      const float2 xq2 = *(const float2*)&xq[((size_t)(m * 1024 + q0 + qg)) * 2];
      const u32 dqpair = pkt(xq2.x - xk2.x, xq2.y - xk2.y);
      // layer-1 B-frag: dims rows lg*8..+7, pair col = l15
      const u32 u0 = (lg == 0) ? dqpair : ((lg == 1) ? p3 : 0u);
      const u32 u1 = (lg == 0) ? p0 : u1base;
      const u32 u2 = (lg == 0) ? p1 : 0u;
      const u32 u3 = (lg == 0) ? p2 : 0u;
      const s16x8 bf1 = mk8(u0, u1, u2, u3);
      const f32x4 h0 = MFMA16(w1a[0], bf1, Z4, 0, 0, 0);
      const f32x4 h1 = MFMA16(w1a[1], bf1, Z4, 0, 0, 0);
      // relu + pack straight into layer-2 B-frag (channel-permuted L1 rows)
      const s16x8 bf2 = mk8(pkt(fmaxf(h0[0], 0.f), fmaxf(h0[1], 0.f)),
                            pkt(fmaxf(h0[2], 0.f), fmaxf(h0[3], 0.f)),
                            pkt(fmaxf(h1[0], 0.f), fmaxf(h1[1], 0.f)),
                            pkt(fmaxf(h1[2], 0.f), fmaxf(h1[3], 0.f)));
      const f32x4 Lg = MFMA16(w2a, bf2, b2v, 0, 0, 0);  // bias via C-in
      // logits (pre-scaled by log2e): lane (l15=pair, lg<2) holds h = lg*4+i
      if (lglo) {
        #pragma unroll
        for (int i = 0; i < 4; ++i) {
          const float e = exp2f(Lg[i]);  // raw v_exp_f32
          P_s[lg * 4 + i][qg][kk] = (u16)(__builtin_bit_cast(unsigned, e) >> 16);
        }
      }
    }
    __syncthreads();  // P complete

    // ---- PV + sum MFMA: heads {2wid, 2wid+1}, V frags from global (L2) ----
    #pragma unroll
    for (int hh = 0; hh < 2; ++hh) {
      const int h = wid * 2 + hh;
      s16x8 pa[2];
      #pragma unroll
      for (int ks = 0; ks < 2; ++ks)
        pa[ks] = *(const s16x8*)&P_s[h][l15][ks * 32 + lg * 8];
      #pragma unroll
      for (int dh = 0; dh < 2; ++dh) {
        const size_t vrow = ((size_t)(m * 256 + h * 32 + dh * 16 + l15)) * 1024 + kg;
        #pragma unroll
        for (int ks = 0; ks < 2; ++ks) {
          const s16x8 b = *(const s16x8*)&vT[vrow + ks * 32 + lg * 8];
          acc_pv[hh][dh] = MFMA16(pa[ks], b, acc_pv[hh][dh], 0, 0, 0);
        }
      }
      #pragma unroll
      for (int ks = 0; ks < 2; ++ks)
        acc_sum[hh] = MFMA16(pa[ks], ones, acc_sum[hh], 0, 0, 0);
    }
    __syncthreads();  // P consumed
  }

  // ---- epilogue: store bf16 partial PV and f32 partial L ----
  #pragma unroll
  for (int hh = 0; hh < 2; ++hh) {
    const int h = wid * 2 + hh;
    #pragma unroll
    for (int dh = 0; dh < 2; ++dh)
      #pragma unroll
      for (int i = 0; i < 4; ++i) {
        const int qr = lg * 4 + i;
        myPre[((size_t)(m * 1024 + q0 + qr)) * 256 + h * 32 + dh * 16 + l15] =
            f2b(acc_pv[hh][dh][i]);
      }
    if (l15 == 0) {
      #pragma unroll
      for (int i = 0; i < 4; ++i)
        myL[((size_t)(m * 1024 + q0 + lg * 4 + i)) * 8 + h] = acc_sum[hh][i];
    }
  }
}

// ---------------- output projection with 2-way partial combine -------------
__global__ __launch_bounds__(256) void outp_kernel(
    const u16* __restrict__ preP, const float* __restrict__ Lb,
    const u16* __restrict__ WoT,
    const float* __restrict__ bout, float* __restrict__ out) {
  const int n0 = blockIdx.x * 64;
  const int j0 = blockIdx.y * 64;
  const int tid = threadIdx.x;
  const int lane = tid & 63, wid = tid >> 6;
  const int l15 = lane & 15, lg = lane >> 4;
  const int wn = wid & 1, wj = wid >> 1;
  __shared__ u16 As[64][40];
  __shared__ u16 Bs[64][40];
  f32x4 acc[2][2];
  #pragma unroll
  for (int a = 0; a < 2; ++a)
    #pragma unroll
    for (int b = 0; b < 2; ++b) acc[a][b] = (f32x4){0.f, 0.f, 0.f, 0.f};

  const size_t PSTRIDE = (size_t)8192 * 256;
  const size_t LSTRIDE = (size_t)8192 * 8;

  for (int ks = 0; ks < 8; ++ks) {
    const int d0 = ks * 32;
    const int r = tid >> 2, cb = (tid & 3) * 8;
    const size_t row = (size_t)(n0 + r);
    const float Ls = Lb[row * 8 + ks] + Lb[LSTRIDE + row * 8 + ks];
    const float inv = 1.0f / Ls;
    const s16x8 p0 = *(const s16x8*)&preP[row * 256 + d0 + cb];
    const s16x8 p1 = *(const s16x8*)&preP[PSTRIDE + row * 256 + d0 + cb];
    s16x8 t;
    #pragma unroll
    for (int j = 0; j < 8; ++j)
      t[j] = (short)f2b((b2f((u16)p0[j]) + b2f((u16)p1[j])) * inv);
    *(s16x8*)&As[r][cb] = t;
    *(s16x8*)&Bs[r][cb] = *(const s16x8*)&WoT[(size_t)(j0 + r) * 256 + d0 + cb];
    __syncthreads();
    s16x8 a0 = *(const s16x8*)&As[wn * 32 + l15][lg * 8];
    s16x8 a1 = *(const s16x8*)&As[wn * 32 + 16 + l15][lg * 8];
    s16x8 b0 = *(const s16x8*)&Bs[wj * 32 + l15][lg * 8];
    s16x8 b1 = *(const s16x8*)&Bs[wj * 32 + 16 + l15][lg * 8];
    acc[0][0] = MFMA16(a0, b0, acc[0][0], 0, 0, 0);
    acc[0][1] = MFMA16(a0, b1, acc[0][1], 0, 0, 0);
    acc[1][0] = MFMA16(a1, b0, acc[1][0], 0, 0, 0);
    acc[1][1] = MFMA16(a1, b1, acc[1][1], 0, 0, 0);
    __syncthreads();
  }
  #pragma unroll
  for (int sn = 0; sn < 2; ++sn)
    #pragma unroll
    for (int sj = 0; sj < 2; ++sj)
      #pragma unroll
      for (int i = 0; i < 4; ++i) {
        int n = n0 + wn * 32 + sn * 16 + lg * 4 + i;
        int j = j0 + wj * 32 + sj * 16 + l15;
        out[(size_t)n * 256 + j] = acc[sn][sj][i] + bout[j];
      }
}

extern "C" void kernel_launch(void* const* d_in, const int* in_sizes, int n_in,
                              void* d_out, int out_size, void* d_ws, size_t ws_size,
                              hipStream_t stream) {
  const float* zq = (const float*)d_in[0];
  const float* zk = (const float*)d_in[1];
  const float* zv = (const float*)d_in[2];
  const float* xq = (const float*)d_in[3];
  const float* xkv = (const float*)d_in[4];
  const float* Wq = (const float*)d_in[5];
  const float* Wk = (const float*)d_in[6];
  const float* Wv = (const float*)d_in[7];
  const float* Wo = (const float*)d_in[8];
  const float* bout = (const float*)d_in[9];
  const float* W1 = (const float*)d_in[10];
  const float* b1 = (const float*)d_in[11];
  const float* W2 = (const float*)d_in[12];
  const float* b2 = (const float*)d_in[13];
  float* out = (float*)d_out;

  const size_t MB = (size_t)1 << 20;
  char* ws = (char*)d_ws;
  u16* qb   = (u16*)(ws + 0 * MB);
  u16* kb   = (u16*)(ws + 4 * MB);
  u16* vT   = (u16*)(ws + 8 * MB);
  u16* preP = (u16*)(ws + 12 * MB);      // 2 x 4 MB (bf16 partial PV)
  float* Lb = (float*)(ws + 20 * MB);    // 2 x 256 KB (f32 partial L)
  char* wbase = ws + 21 * MB;
  u16* WqT  = (u16*)(wbase + 0 * (128 << 10));
  u16* WkT  = (u16*)(wbase + 1 * (128 << 10));
  u16* WvT  = (u16*)(wbase + 2 * (128 << 10));
  u16* WoT  = (u16*)(wbase + 3 * (128 << 10));

  wtrans_kernel<<<dim3(4, 256), dim3(256), 0, stream>>>(Wq, Wk, Wv, Wo, WqT, WkT, WvT, WoT);
  proj_kernel<<<dim3(128, 4, 3), dim3(256), 0, stream>>>(zq, zk, zv, WqT, WkT, WvT, qb, kb, vT);
  attn_kernel<<<dim3(1024), dim3(256), 0, stream>>>(qb, kb, vT, xq, xkv, W1, b1, W2, b2, preP, Lb);
  outp_kernel<<<dim3(128, 4), dim3(256), 0, stream>>>(preP, Lb, WoT, bout, out);
  copyxq_kernel<<<dim3(64), dim3(256), 0, stream>>>(xq, out + (size_t)8 * 1024 * 256);
}

// Round 20
// 135.127 us; speedup vs baseline: 1.1618x; 1.1618x over previous
//
#include <hip/hip_runtime.h>

typedef float f32x4 __attribute__((ext_vector_type(4)));
typedef short s16x8 __attribute__((ext_vector_type(8)));
typedef unsigned short u16;
typedef unsigned int u32;

#define MFMA16 __builtin_amdgcn_mfma_f32_16x16x32_bf16
#define SCALE 0.17677669529663687f  // 32^-0.5
#define LOG2E 1.44269504088896f

__device__ __forceinline__ u16 f2b(float f) {
  union { float f; unsigned u; } x; x.f = f;
  unsigned r = x.u + 0x7fffu + ((x.u >> 16) & 1u);
  return (u16)(r >> 16);
}
__device__ __forceinline__ float b2f(u16 s) {
  union { unsigned u; float f; } x; x.u = ((unsigned)s) << 16;
  return x.f;
}
// pack two f32 -> u32 of two bf16 (low = a, high = b), TRUNCATE, 1 inst
__device__ __forceinline__ u32 pkt(float a, float b) {
  return __builtin_amdgcn_perm(__builtin_bit_cast(u32, b),
                               __builtin_bit_cast(u32, a), 0x07060302u);
}
__device__ __forceinline__ u32 bperm(int idx, u32 src) {
  return (u32)__builtin_amdgcn_ds_bpermute(idx, (int)src);
}
__device__ __forceinline__ s16x8 mk8(u32 a, u32 b, u32 c, u32 d) {
  union { u32 w[4]; s16x8 v; } u;
  u.w[0] = a; u.w[1] = b; u.w[2] = c; u.w[3] = d;
  return u.v;
}

// ---------------- weight transpose + bf16 cast: WT[j][d] = bf16(W[d][j]) ----
__global__ __launch_bounds__(256) void wtrans_kernel(
    const float* __restrict__ Wq, const float* __restrict__ Wk,
    const float* __restrict__ Wv, const float* __restrict__ Wo,
    u16* __restrict__ WqT, u16* __restrict__ WkT,
    u16* __restrict__ WvT, u16* __restrict__ WoT) {
  const float* src; u16* dst;
  switch (blockIdx.x) {
    case 0: src = Wq; dst = WqT; break;
    case 1: src = Wk; dst = WkT; break;
    case 2: src = Wv; dst = WvT; break;
    default: src = Wo; dst = WoT; break;
  }
  int j = blockIdx.y;
  int d = threadIdx.x;
  dst[j * 256 + d] = f2b(src[d * 256 + j]);
}

// ---------------- xq passthrough (output 1) --------------------------------
__global__ __launch_bounds__(256) void copyxq_kernel(const float* __restrict__ xq,
                                                     float* __restrict__ dst) {
  int i = blockIdx.x * 256 + threadIdx.x;
  dst[i] = xq[i];
}

// ---------------- QKV projection: bf16 MFMA GEMM ---------------------------
__global__ __launch_bounds__(256) void proj_kernel(
    const float* __restrict__ zq, const float* __restrict__ zk,
    const float* __restrict__ zv,
    const u16* __restrict__ WqT, const u16* __restrict__ WkT,
    const u16* __restrict__ WvT,
    u16* __restrict__ qb, u16* __restrict__ kb, u16* __restrict__ vT) {
  const int mat = blockIdx.z;
  const float* Z = (mat == 0) ? zq : (mat == 1) ? zk : zv;
  const u16* WT = (mat == 0) ? WqT : (mat == 1) ? WkT : WvT;
  const int n0 = blockIdx.x * 64;
  const int j0 = blockIdx.y * 64;
  const int tid = threadIdx.x;
  const int lane = tid & 63, wid = tid >> 6;
  const int l15 = lane & 15, lg = lane >> 4;
  const int wn = wid & 1, wj = wid >> 1;

  __shared__ u16 As[64][40];
  __shared__ u16 Bs[64][40];

  f32x4 acc[2][2];
  #pragma unroll
  for (int a = 0; a < 2; ++a)
    #pragma unroll
    for (int b = 0; b < 2; ++b) acc[a][b] = (f32x4){0.f, 0.f, 0.f, 0.f};

  for (int ks = 0; ks < 8; ++ks) {
    const int d0 = ks * 32;
    const int r = tid >> 2, cb = (tid & 3) * 8;
    const float* zsrc = &Z[(size_t)(n0 + r) * 256 + d0 + cb];
    s16x8 t;
    #pragma unroll
    for (int j = 0; j < 8; ++j) t[j] = (short)f2b(zsrc[j]);
    *(s16x8*)&As[r][cb] = t;
    *(s16x8*)&Bs[r][cb] = *(const s16x8*)&WT[(size_t)(j0 + r) * 256 + d0 + cb];
    __syncthreads();
    s16x8 a0 = *(const s16x8*)&As[wn * 32 + l15][lg * 8];
    s16x8 a1 = *(const s16x8*)&As[wn * 32 + 16 + l15][lg * 8];
    s16x8 b0 = *(const s16x8*)&Bs[wj * 32 + l15][lg * 8];
    s16x8 b1 = *(const s16x8*)&Bs[wj * 32 + 16 + l15][lg * 8];
    acc[0][0] = MFMA16(a0, b0, acc[0][0], 0, 0, 0);
    acc[0][1] = MFMA16(a0, b1, acc[0][1], 0, 0, 0);
    acc[1][0] = MFMA16(a1, b0, acc[1][0], 0, 0, 0);
    acc[1][1] = MFMA16(a1, b1, acc[1][1], 0, 0, 0);
    __syncthreads();
  }
  #pragma unroll
  for (int sn = 0; sn < 2; ++sn)
    #pragma unroll
    for (int sj = 0; sj < 2; ++sj)
      #pragma unroll
      for (int i = 0; i < 4; ++i) {
        int n = n0 + wn * 32 + sn * 16 + lg * 4 + i;
        int j = j0 + wj * 32 + sj * 16 + l15;
        float av = acc[sn][sj][i];
        if (mat == 0) av *= SCALE;
        u16 val = f2b(av);
        if (mat == 0) {
          qb[(size_t)n * 256 + j] = val;
        } else if (mat == 1) {
          kb[(size_t)n * 256 + j] = val;
        } else {
          int mm = n >> 10, nn = n & 1023;
          vT[((size_t)(mm * 256 + j)) * 1024 + nn] = val;
        }
      }
}

// ---------------- fused TE attention: 4-wave blocks, 64-key tiles ----------
// 1024 blocks x 256 thr (4 waves). Decode: m = bid&7 (XCD affinity),
// qblk = (bid>>3)&63, kz = bid>>9 (512-key slice, 8 tiles of 64).
// Wave wid owns keys wid*16..+15 of each 64-tile for dots/MLP; heads
// {2*wid, 2*wid+1} for PV. P_s DOUBLE-BUFFERED [2][8h][16q][72] = 36864 B:
// one barrier per kt (write buf kt&1 -> barrier -> read buf kt&1; the
// next tile's barrier covers the read->write hazard since each wave's
// kt-PV precedes its kt+1-barrier in program order).
// launch_bounds (256,4): NEVER below 4 -- (256,5) forces VGPR 48 and
// spills acc (R13/R19: FETCH 10 -> 160+ MB). AGPR granule makes the
// effective floor 64 arch + 64 acc = 128 regs.
__global__ __launch_bounds__(256, 4) void attn_kernel(
    const u16* __restrict__ qb, const u16* __restrict__ kb,
    const u16* __restrict__ vT,
    const float* __restrict__ xq, const float* __restrict__ xkv,
    const float* __restrict__ W1, const float* __restrict__ b1,
    const float* __restrict__ W2, const float* __restrict__ b2,
    u16* __restrict__ preP, float* __restrict__ Lb) {
  const int bid = blockIdx.x;
  const int m = bid & 7;                 // XCD affinity: batch per XCD
  const int q0 = ((bid >> 3) & 63) * 16;
  const int kz = bid >> 9;               // 0..1
  const int tid = threadIdx.x;
  const int lane = tid & 63;
  const int wid = tid >> 6;              // 0..3
  const int l15 = lane & 15;
  const int lg = lane >> 4;
  const int kk = wid * 16 + l15;         // key in 64-tile

  u16* myPre = preP + (size_t)kz * (8192 * 256);
  float* myL = Lb + (size_t)kz * (8192 * 8);

  __shared__ u16 P_s[2][8][16][72];  // 36864 B, double-buffered by kt&1

  // resident W1^T A-fragments, channel-permuted:
  // row r of block b holds channel c = 8*(r>>2) + 4*b + (r&3)
  s16x8 w1a[2];
  #pragma unroll
  for (int cblk = 0; cblk < 2; ++cblk) {
    const int c = 8 * (l15 >> 2) + 4 * cblk + (l15 & 3);
    #pragma unroll
    for (int j = 0; j < 8; ++j) {
      const int dim = lg * 8 + j;
      u16 v = 0;
      if (dim < 10) v = f2b(W1[dim * 32 + c]);
      else if (dim == 10) v = f2b(b1[c]);
      w1a[cblk][j] = (short)v;
    }
  }
  // resident W2^T A-fragment (pre-scaled by log2e):
  // A[row=h=l15 (<8)][K=c=lg*8+j] (identity c-order)
  s16x8 w2a;
  #pragma unroll
  for (int j = 0; j < 8; ++j) {
    const int c = lg * 8 + j;
    w2a[j] = (short)((l15 < 8) ? f2b(W2[c * 8 + l15] * LOG2E) : (u16)0);
  }
  // b2 (pre-scaled) as MFMA C-in: lane (l15,lg) C row = lg*4+i = head (lg<2)
  f32x4 b2v;
  #pragma unroll
  for (int i = 0; i < 4; ++i) b2v[i] = b2[(lg & 1) * 4 + i] * LOG2E;

  // bpermute index registers (byte-indexed: lane*4)
  const int idx10 = (l15 + 0) * 4;   // pull from lg'=0
  const int idx11 = (l15 + 16) * 4;  // lg'=1
  const int idx12 = (l15 + 32) * 4;  // lg'=2
  const int idx13 = (l15 + 48) * 4;  // lg'=3
  const u32 u1base = (lg == 1) ? 0x00003F80u : 0u;  // dims(10,11)=(1.0,0)
  const bool lglo = (lg < 2);

  s16x8 ones;
  #pragma unroll
  for (int j = 0; j < 8; ++j) ones[j] = (l15 == 0) ? (short)0x3F80 : (short)0;

  // hoisted Q A-fragments (kt-invariant): 8 x 16B
  s16x8 qfr[8];
  #pragma unroll
  for (int h = 0; h < 8; ++h)
    qfr[h] = *(const s16x8*)&qb[((size_t)(m * 1024 + q0 + l15)) * 256 + h * 32 + lg * 8];

  f32x4 acc_pv[2][2];   // [head hh][d half]
  f32x4 acc_sum[2];     // [head hh]
  #pragma unroll
  for (int hh = 0; hh < 2; ++hh) {
    acc_pv[hh][0] = (f32x4){0.f, 0.f, 0.f, 0.f};
    acc_pv[hh][1] = (f32x4){0.f, 0.f, 0.f, 0.f};
    acc_sum[hh] = (f32x4){0.f, 0.f, 0.f, 0.f};
  }
  const f32x4 Z4 = (f32x4){0.f, 0.f, 0.f, 0.f};

  for (int kt = 0; kt < 8; ++kt) {
    const int pb = kt & 1;              // P_s buffer parity
    const int kg = kz * 512 + kt * 64;  // global key base of 64-tile
    const float2 xk2 = *(const float2*)&xkv[((size_t)(m * 1024 + kg + kk)) * 2];

    // ---- dots: 8 MFMA (per head), K frags from global (L2) ----
    u32 dpk[4][4];
    {
      f32x4 dacc[8];
      #pragma unroll
      for (int h = 0; h < 8; ++h) {
        const s16x8 b = *(const s16x8*)&kb[((size_t)(m * 1024 + kg + kk)) * 256 + h * 32 + lg * 8];
        dacc[h] = MFMA16(qfr[h], b, Z4, 0, 0, 0);
      }
      // lane (l15,lg) holds q=lg*4+i, key=l15: pack head-pairs to bf16
      #pragma unroll
      for (int i = 0; i < 4; ++i)
        #pragma unroll
        for (int j = 0; j < 4; ++j)
          dpk[i][j] = pkt(dacc[2 * j][i], dacc[2 * j + 1][i]);
    }

    // ---- 16 pair-groups: qg = one q x this wave's 16 keys ----
    #pragma unroll 8
    for (int qg = 0; qg < 16; ++qg) {
      const int isrc = qg & 3;
      const int idxq = (qg >> 2) == 0 ? idx10 : (qg >> 2) == 1 ? idx11
                     : (qg >> 2) == 2 ? idx12 : idx13;
      // pull q=qg's dot-pairs from lane (l15, qg>>2); own key stays l15
      const u32 p0 = bperm(idxq, dpk[isrc][0]);
      const u32 p1 = bperm(idxq, dpk[isrc][1]);
      const u32 p2 = bperm(idxq, dpk[isrc][2]);
      const u32 p3 = bperm(idxq, dpk[isrc][3]);
      // position diff (uniform xq load, per-lane xk)
      const float2 xq2 = *(const float2*)&xq[((size_t)(m * 1024 + q0 + qg)) * 2];
      const u32 dqpair = pkt(xq2.x - xk2.x, xq2.y - xk2.y);
      // layer-1 B-frag: dims rows lg*8..+7, pair col = l15
      const u32 u0 = (lg == 0) ? dqpair : ((lg == 1) ? p3 : 0u);
      const u32 u1 = (lg == 0) ? p0 : u1base;
      const u32 u2 = (lg == 0) ? p1 : 0u;
      const u32 u3 = (lg == 0) ? p2 : 0u;
      const s16x8 bf1 = mk8(u0, u1, u2, u3);
      const f32x4 h0 = MFMA16(w1a[0], bf1, Z4, 0, 0, 0);
      const f32x4 h1 = MFMA16(w1a[1], bf1, Z4, 0, 0, 0);
      // relu + pack straight into layer-2 B-frag (channel-permuted L1 rows)
      const s16x8 bf2 = mk8(pkt(fmaxf(h0[0], 0.f), fmaxf(h0[1], 0.f)),
                            pkt(fmaxf(h0[2], 0.f), fmaxf(h0[3], 0.f)),
                            pkt(fmaxf(h1[0], 0.f), fmaxf(h1[1], 0.f)),
                            pkt(fmaxf(h1[2], 0.f), fmaxf(h1[3], 0.f)));
      const f32x4 Lg = MFMA16(w2a, bf2, b2v, 0, 0, 0);  // bias via C-in
      // logits (pre-scaled by log2e): lane (l15=pair, lg<2) holds h = lg*4+i
      if (lglo) {
        #pragma unroll
        for (int i = 0; i < 4; ++i) {
          const float e = exp2f(Lg[i]);  // raw v_exp_f32
          P_s[pb][lg * 4 + i][qg][kk] = (u16)(__builtin_bit_cast(unsigned, e) >> 16);
        }
      }
    }
    __syncthreads();  // P[pb] complete (sole barrier this kt)

    // ---- PV + sum MFMA: heads {2wid, 2wid+1}, V frags from global (L2) ----
    #pragma unroll
    for (int hh = 0; hh < 2; ++hh) {
      const int h = wid * 2 + hh;
      s16x8 pa[2];
      #pragma unroll
      for (int ks = 0; ks < 2; ++ks)
        pa[ks] = *(const s16x8*)&P_s[pb][h][l15][ks * 32 + lg * 8];
      #pragma unroll
      for (int dh = 0; dh < 2; ++dh) {
        const size_t vrow = ((size_t)(m * 256 + h * 32 + dh * 16 + l15)) * 1024 + kg;
        #pragma unroll
        for (int ks = 0; ks < 2; ++ks) {
          const s16x8 b = *(const s16x8*)&vT[vrow + ks * 32 + lg * 8];
          acc_pv[hh][dh] = MFMA16(pa[ks], b, acc_pv[hh][dh], 0, 0, 0);
        }
      }
      #pragma unroll
      for (int ks = 0; ks < 2; ++ks)
        acc_sum[hh] = MFMA16(pa[ks], ones, acc_sum[hh], 0, 0, 0);
    }
    // no trailing barrier: next kt writes the OTHER buffer; its barrier
    // (after next MLP) orders these reads before the buffer's next reuse.
  }

  // ---- epilogue: store bf16 partial PV and f32 partial L ----
  #pragma unroll
  for (int hh = 0; hh < 2; ++hh) {
    const int h = wid * 2 + hh;
    #pragma unroll
    for (int dh = 0; dh < 2; ++dh)
      #pragma unroll
      for (int i = 0; i < 4; ++i) {
        const int qr = lg * 4 + i;
        myPre[((size_t)(m * 1024 + q0 + qr)) * 256 + h * 32 + dh * 16 + l15] =
            f2b(acc_pv[hh][dh][i]);
      }
    if (l15 == 0) {
      #pragma unroll
      for (int i = 0; i < 4; ++i)
        myL[((size_t)(m * 1024 + q0 + lg * 4 + i)) * 8 + h] = acc_sum[hh][i];
    }
  }
}

// ---------------- output projection with 2-way partial combine -------------
__global__ __launch_bounds__(256) void outp_kernel(
    const u16* __restrict__ preP, const float* __restrict__ Lb,
    const u16* __restrict__ WoT,
    const float* __restrict__ bout, float* __restrict__ out) {
  const int n0 = blockIdx.x * 64;
  const int j0 = blockIdx.y * 64;
  const int tid = threadIdx.x;
  const int lane = tid & 63, wid = tid >> 6;
  const int l15 = lane & 15, lg = lane >> 4;
  const int wn = wid & 1, wj = wid >> 1;
  __shared__ u16 As[64][40];
  __shared__ u16 Bs[64][40];
  f32x4 acc[2][2];
  #pragma unroll
  for (int a = 0; a < 2; ++a)
    #pragma unroll
    for (int b = 0; b < 2; ++b) acc[a][b] = (f32x4){0.f, 0.f, 0.f, 0.f};

  const size_t PSTRIDE = (size_t)8192 * 256;
  const size_t LSTRIDE = (size_t)8192 * 8;

  for (int ks = 0; ks < 8; ++ks) {
    const int d0 = ks * 32;
    const int r = tid >> 2, cb = (tid & 3) * 8;
    const size_t row = (size_t)(n0 + r);
    const float Ls = Lb[row * 8 + ks] + Lb[LSTRIDE + row * 8 + ks];
    const float inv = 1.0f / Ls;
    const s16x8 p0 = *(const s16x8*)&preP[row * 256 + d0 + cb];
    const s16x8 p1 = *(const s16x8*)&preP[PSTRIDE + row * 256 + d0 + cb];
    s16x8 t;
    #pragma unroll
    for (int j = 0; j < 8; ++j)
      t[j] = (short)f2b((b2f((u16)p0[j]) + b2f((u16)p1[j])) * inv);
    *(s16x8*)&As[r][cb] = t;
    *(s16x8*)&Bs[r][cb] = *(const s16x8*)&WoT[(size_t)(j0 + r) * 256 + d0 + cb];
    __syncthreads();
    s16x8 a0 = *(const s16x8*)&As[wn * 32 + l15][lg * 8];
    s16x8 a1 = *(const s16x8*)&As[wn * 32 + 16 + l15][lg * 8];
    s16x8 b0 = *(const s16x8*)&Bs[wj * 32 + l15][lg * 8];
    s16x8 b1 = *(const s16x8*)&Bs[wj * 32 + 16 + l15][lg * 8];
    acc[0][0] = MFMA16(a0, b0, acc[0][0], 0, 0, 0);
    acc[0][1] = MFMA16(a0, b1, acc[0][1], 0, 0, 0);
    acc[1][0] = MFMA16(a1, b0, acc[1][0], 0, 0, 0);
    acc[1][1] = MFMA16(a1, b1, acc[1][1], 0, 0, 0);
    __syncthreads();
  }
  #pragma unroll
  for (int sn = 0; sn < 2; ++sn)
    #pragma unroll
    for (int sj = 0; sj < 2; ++sj)
      #pragma unroll
      for (int i = 0; i < 4; ++i) {
        int n = n0 + wn * 32 + sn * 16 + lg * 4 + i;
        int j = j0 + wj * 32 + sj * 16 + l15;
        out[(size_t)n * 256 + j] = acc[sn][sj][i] + bout[j];
      }
}

extern "C" void kernel_launch(void* const* d_in, const int* in_sizes, int n_in,
                              void* d_out, int out_size, void* d_ws, size_t ws_size,
                              hipStream_t stream) {
  const float* zq = (const float*)d_in[0];
  const float* zk = (const float*)d_in[1];
  const float* zv = (const float*)d_in[2];
  const float* xq = (const float*)d_in[3];
  const float* xkv = (const float*)d_in[4];
  const float* Wq = (const float*)d_in[5];
  const float* Wk = (const float*)d_in[6];
  const float* Wv = (const float*)d_in[7];
  const float* Wo = (const float*)d_in[8];
  const float* bout = (const float*)d_in[9];
  const float* W1 = (const float*)d_in[10];
  const float* b1 = (const float*)d_in[11];
  const float* W2 = (const float*)d_in[12];
  const float* b2 = (const float*)d_in[13];
  float* out = (float*)d_out;

  const size_t MB = (size_t)1 << 20;
  char* ws = (char*)d_ws;
  u16* qb   = (u16*)(ws + 0 * MB);
  u16* kb   = (u16*)(ws + 4 * MB);
  u16* vT   = (u16*)(ws + 8 * MB);
  u16* preP = (u16*)(ws + 12 * MB);      // 2 x 4 MB (bf16 partial PV)
  float* Lb = (float*)(ws + 20 * MB);    // 2 x 256 KB (f32 partial L)
  char* wbase = ws + 21 * MB;
  u16* WqT  = (u16*)(wbase + 0 * (128 << 10));
  u16* WkT  = (u16*)(wbase + 1 * (128 << 10));
  u16* WvT  = (u16*)(wbase + 2 * (128 << 10));
  u16* WoT  = (u16*)(wbase + 3 * (128 << 10));

  wtrans_kernel<<<dim3(4, 256), dim3(256), 0, stream>>>(Wq, Wk, Wv, Wo, WqT, WkT, WvT, WoT);
  proj_kernel<<<dim3(128, 4, 3), dim3(256), 0, stream>>>(zq, zk, zv, WqT, WkT, WvT, qb, kb, vT);
  attn_kernel<<<dim3(1024), dim3(256), 0, stream>>>(qb, kb, vT, xq, xkv, W1, b1, W2, b2, preP, Lb);
  outp_kernel<<<dim3(128, 4), dim3(256), 0, stream>>>(preP, Lb, WoT, bout, out);
  copyxq_kernel<<<dim3(64), dim3(256), 0, stream>>>(xq, out + (size_t)8 * 1024 * 256);
}

// Round 21
// 127.244 us; speedup vs baseline: 1.2338x; 1.0619x over previous
//
#include <hip/hip_runtime.h>

typedef float f32x4 __attribute__((ext_vector_type(4)));
typedef short s16x8 __attribute__((ext_vector_type(8)));
typedef unsigned short u16;
typedef unsigned int u32;

#define MFMA16 __builtin_amdgcn_mfma_f32_16x16x32_bf16
#define SCALE 0.17677669529663687f  // 32^-0.5
#define LOG2E 1.44269504088896f

__device__ __forceinline__ u16 f2b(float f) {
  union { float f; unsigned u; } x; x.f = f;
  unsigned r = x.u + 0x7fffu + ((x.u >> 16) & 1u);
  return (u16)(r >> 16);
}
__device__ __forceinline__ float b2f(u16 s) {
  union { unsigned u; float f; } x; x.u = ((unsigned)s) << 16;
  return x.f;
}
// pack two f32 -> u32 of two bf16 (low = a, high = b), TRUNCATE, 1 inst
__device__ __forceinline__ u32 pkt(float a, float b) {
  return __builtin_amdgcn_perm(__builtin_bit_cast(u32, b),
                               __builtin_bit_cast(u32, a), 0x07060302u);
}
__device__ __forceinline__ u32 bperm(int idx, u32 src) {
  return (u32)__builtin_amdgcn_ds_bpermute(idx, (int)src);
}
__device__ __forceinline__ s16x8 mk8(u32 a, u32 b, u32 c, u32 d) {
  union { u32 w[4]; s16x8 v; } u;
  u.w[0] = a; u.w[1] = b; u.w[2] = c; u.w[3] = d;
  return u.v;
}

// ---------------- weight transpose + bf16 cast: WT[j][d] = bf16(W[d][j]) ----
__global__ __launch_bounds__(256) void wtrans_kernel(
    const float* __restrict__ Wq, const float* __restrict__ Wk,
    const float* __restrict__ Wv, const float* __restrict__ Wo,
    u16* __restrict__ WqT, u16* __restrict__ WkT,
    u16* __restrict__ WvT, u16* __restrict__ WoT) {
  const float* src; u16* dst;
  switch (blockIdx.x) {
    case 0: src = Wq; dst = WqT; break;
    case 1: src = Wk; dst = WkT; break;
    case 2: src = Wv; dst = WvT; break;
    default: src = Wo; dst = WoT; break;
  }
  int j = blockIdx.y;
  int d = threadIdx.x;
  dst[j * 256 + d] = f2b(src[d * 256 + j]);
}

// ---------------- xq passthrough (output 1) --------------------------------
__global__ __launch_bounds__(256) void copyxq_kernel(const float* __restrict__ xq,
                                                     float* __restrict__ dst) {
  int i = blockIdx.x * 256 + threadIdx.x;
  dst[i] = xq[i];
}

// ---------------- QKV projection: bf16 MFMA GEMM ---------------------------
__global__ __launch_bounds__(256) void proj_kernel(
    const float* __restrict__ zq, const float* __restrict__ zk,
    const float* __restrict__ zv,
    const u16* __restrict__ WqT, const u16* __restrict__ WkT,
    const u16* __restrict__ WvT,
    u16* __restrict__ qb, u16* __restrict__ kb, u16* __restrict__ vT) {
  const int mat = blockIdx.z;
  const float* Z = (mat == 0) ? zq : (mat == 1) ? zk : zv;
  const u16* WT = (mat == 0) ? WqT : (mat == 1) ? WkT : WvT;
  const int n0 = blockIdx.x * 64;
  const int j0 = blockIdx.y * 64;
  const int tid = threadIdx.x;
  const int lane = tid & 63, wid = tid >> 6;
  const int l15 = lane & 15, lg = lane >> 4;
  const int wn = wid & 1, wj = wid >> 1;

  __shared__ u16 As[64][40];
  __shared__ u16 Bs[64][40];

  f32x4 acc[2][2];
  #pragma unroll
  for (int a = 0; a < 2; ++a)
    #pragma unroll
    for (int b = 0; b < 2; ++b) acc[a][b] = (f32x4){0.f, 0.f, 0.f, 0.f};

  for (int ks = 0; ks < 8; ++ks) {
    const int d0 = ks * 32;
    const int r = tid >> 2, cb = (tid & 3) * 8;
    const float* zsrc = &Z[(size_t)(n0 + r) * 256 + d0 + cb];
    s16x8 t;
    #pragma unroll
    for (int j = 0; j < 8; ++j) t[j] = (short)f2b(zsrc[j]);
    *(s16x8*)&As[r][cb] = t;
    *(s16x8*)&Bs[r][cb] = *(const s16x8*)&WT[(size_t)(j0 + r) * 256 + d0 + cb];
    __syncthreads();
    s16x8 a0 = *(const s16x8*)&As[wn * 32 + l15][lg * 8];
    s16x8 a1 = *(const s16x8*)&As[wn * 32 + 16 + l15][lg * 8];
    s16x8 b0 = *(const s16x8*)&Bs[wj * 32 + l15][lg * 8];
    s16x8 b1 = *(const s16x8*)&Bs[wj * 32 + 16 + l15][lg * 8];
    acc[0][0] = MFMA16(a0, b0, acc[0][0], 0, 0, 0);
    acc[0][1] = MFMA16(a0, b1, acc[0][1], 0, 0, 0);
    acc[1][0] = MFMA16(a1, b0, acc[1][0], 0, 0, 0);
    acc[1][1] = MFMA16(a1, b1, acc[1][1], 0, 0, 0);
    __syncthreads();
  }
  #pragma unroll
  for (int sn = 0; sn < 2; ++sn)
    #pragma unroll
    for (int sj = 0; sj < 2; ++sj)
      #pragma unroll
      for (int i = 0; i < 4; ++i) {
        int n = n0 + wn * 32 + sn * 16 + lg * 4 + i;
        int j = j0 + wj * 32 + sj * 16 + l15;
        float av = acc[sn][sj][i];
        if (mat == 0) av *= SCALE;
        u16 val = f2b(av);
        if (mat == 0) {
          qb[(size_t)n * 256 + j] = val;
        } else if (mat == 1) {
          kb[(size_t)n * 256 + j] = val;
        } else {
          int mm = n >> 10, nn = n & 1023;
          vT[((size_t)(mm * 256 + j)) * 1024 + nn] = val;
        }
      }
}

// ---------------- fused TE attention: 4-wave blocks, 64-key tiles ----------
// 1024 blocks x 256 thr (4 waves). Decode: m = bid&7 (XCD affinity),
// qblk = (bid>>3)&63, kz = bid>>9 (512-key slice, 8 tiles of 64).
// Wave wid owns keys wid*16..+15 of each 64-tile for dots/MLP; heads
// {2*wid, 2*wid+1} for PV. P_s DOUBLE-BUFFERED [2][8h][16q][72] = 36864 B,
// one barrier per kt. V fragments PREFETCHED into regs BEFORE the MLP
// phase (T14 async-stage): their ~300cy L2 latency hides under the
// ~1500cy MLP, so the post-barrier PV runs from registers stall-free.
// launch_bounds (256,4): NEVER below 4 -- (256,5) forces VGPR 48 and
// spills acc (R13/R19: FETCH 10 -> 160+ MB).
__global__ __launch_bounds__(256, 4) void attn_kernel(
    const u16* __restrict__ qb, const u16* __restrict__ kb,
    const u16* __restrict__ vT,
    const float* __restrict__ xq, const float* __restrict__ xkv,
    const float* __restrict__ W1, const float* __restrict__ b1,
    const float* __restrict__ W2, const float* __restrict__ b2,
    u16* __restrict__ preP, float* __restrict__ Lb) {
  const int bid = blockIdx.x;
  const int m = bid & 7;                 // XCD affinity: batch per XCD
  const int q0 = ((bid >> 3) & 63) * 16;
  const int kz = bid >> 9;               // 0..1
  const int tid = threadIdx.x;
  const int lane = tid & 63;
  const int wid = tid >> 6;              // 0..3
  const int l15 = lane & 15;
  const int lg = lane >> 4;
  const int kk = wid * 16 + l15;         // key in 64-tile

  u16* myPre = preP + (size_t)kz * (8192 * 256);
  float* myL = Lb + (size_t)kz * (8192 * 8);

  __shared__ u16 P_s[2][8][16][72];  // 36864 B, double-buffered by kt&1

  // resident W1^T A-fragments, channel-permuted:
  // row r of block b holds channel c = 8*(r>>2) + 4*b + (r&3)
  s16x8 w1a[2];
  #pragma unroll
  for (int cblk = 0; cblk < 2; ++cblk) {
    const int c = 8 * (l15 >> 2) + 4 * cblk + (l15 & 3);
    #pragma unroll
    for (int j = 0; j < 8; ++j) {
      const int dim = lg * 8 + j;
      u16 v = 0;
      if (dim < 10) v = f2b(W1[dim * 32 + c]);
      else if (dim == 10) v = f2b(b1[c]);
      w1a[cblk][j] = (short)v;
    }
  }
  // resident W2^T A-fragment (pre-scaled by log2e):
  // A[row=h=l15 (<8)][K=c=lg*8+j] (identity c-order)
  s16x8 w2a;
  #pragma unroll
  for (int j = 0; j < 8; ++j) {
    const int c = lg * 8 + j;
    w2a[j] = (short)((l15 < 8) ? f2b(W2[c * 8 + l15] * LOG2E) : (u16)0);
  }
  // b2 (pre-scaled) as MFMA C-in: lane (l15,lg) C row = lg*4+i = head (lg<2)
  f32x4 b2v;
  #pragma unroll
  for (int i = 0; i < 4; ++i) b2v[i] = b2[(lg & 1) * 4 + i] * LOG2E;

  // bpermute index registers (byte-indexed: lane*4)
  const int idx10 = (l15 + 0) * 4;   // pull from lg'=0
  const int idx11 = (l15 + 16) * 4;  // lg'=1
  const int idx12 = (l15 + 32) * 4;  // lg'=2
  const int idx13 = (l15 + 48) * 4;  // lg'=3
  const u32 u1base = (lg == 1) ? 0x00003F80u : 0u;  // dims(10,11)=(1.0,0)
  const bool lglo = (lg < 2);

  s16x8 ones;
  #pragma unroll
  for (int j = 0; j < 8; ++j) ones[j] = (l15 == 0) ? (short)0x3F80 : (short)0;

  // hoisted Q A-fragments (kt-invariant): 8 x 16B
  s16x8 qfr[8];
  #pragma unroll
  for (int h = 0; h < 8; ++h)
    qfr[h] = *(const s16x8*)&qb[((size_t)(m * 1024 + q0 + l15)) * 256 + h * 32 + lg * 8];

  f32x4 acc_pv[2][2];   // [head hh][d half]
  f32x4 acc_sum[2];     // [head hh]
  #pragma unroll
  for (int hh = 0; hh < 2; ++hh) {
    acc_pv[hh][0] = (f32x4){0.f, 0.f, 0.f, 0.f};
    acc_pv[hh][1] = (f32x4){0.f, 0.f, 0.f, 0.f};
    acc_sum[hh] = (f32x4){0.f, 0.f, 0.f, 0.f};
  }
  const f32x4 Z4 = (f32x4){0.f, 0.f, 0.f, 0.f};

  for (int kt = 0; kt < 8; ++kt) {
    const int pb = kt & 1;              // P_s buffer parity
    const int kg = kz * 512 + kt * 64;  // global key base of 64-tile
    const float2 xk2 = *(const float2*)&xkv[((size_t)(m * 1024 + kg + kk)) * 2];

    // ---- dots: 8 MFMA (per head), K frags from global (L2) ----
    u32 dpk[4][4];
    {
      f32x4 dacc[8];
      #pragma unroll
      for (int h = 0; h < 8; ++h) {
        const s16x8 b = *(const s16x8*)&kb[((size_t)(m * 1024 + kg + kk)) * 256 + h * 32 + lg * 8];
        dacc[h] = MFMA16(qfr[h], b, Z4, 0, 0, 0);
      }
      // lane (l15,lg) holds q=lg*4+i, key=l15: pack head-pairs to bf16
      #pragma unroll
      for (int i = 0; i < 4; ++i)
        #pragma unroll
        for (int j = 0; j < 4; ++j)
          dpk[i][j] = pkt(dacc[2 * j][i], dacc[2 * j + 1][i]);
    }

    // ---- T14: issue V fragment loads NOW; latency hides under MLP ----
    s16x8 vfr[2][2][2];  // [head hh][d half][k slice]
    #pragma unroll
    for (int hh = 0; hh < 2; ++hh) {
      const int h = wid * 2 + hh;
      #pragma unroll
      for (int dh = 0; dh < 2; ++dh) {
        const size_t vrow = ((size_t)(m * 256 + h * 32 + dh * 16 + l15)) * 1024 + kg;
        #pragma unroll
        for (int ks = 0; ks < 2; ++ks)
          vfr[hh][dh][ks] = *(const s16x8*)&vT[vrow + ks * 32 + lg * 8];
      }
    }

    // ---- 16 pair-groups: qg = one q x this wave's 16 keys ----
    #pragma unroll 8
    for (int qg = 0; qg < 16; ++qg) {
      const int isrc = qg & 3;
      const int idxq = (qg >> 2) == 0 ? idx10 : (qg >> 2) == 1 ? idx11
                     : (qg >> 2) == 2 ? idx12 : idx13;
      // pull q=qg's dot-pairs from lane (l15, qg>>2); own key stays l15
      const u32 p0 = bperm(idxq, dpk[isrc][0]);
      const u32 p1 = bperm(idxq, dpk[isrc][1]);
      const u32 p2 = bperm(idxq, dpk[isrc][2]);
      const u32 p3 = bperm(idxq, dpk[isrc][3]);
      // position diff (uniform xq load, per-lane xk)
      const float2 xq2 = *(const float2*)&xq[((size_t)(m * 1024 + q0 + qg)) * 2];
      const u32 dqpair = pkt(xq2.x - xk2.x, xq2.y - xk2.y);
      // layer-1 B-frag: dims rows lg*8..+7, pair col = l15
      const u32 u0 = (lg == 0) ? dqpair : ((lg == 1) ? p3 : 0u);
      const u32 u1 = (lg == 0) ? p0 : u1base;
      const u32 u2 = (lg == 0) ? p1 : 0u;
      const u32 u3 = (lg == 0) ? p2 : 0u;
      const s16x8 bf1 = mk8(u0, u1, u2, u3);
      const f32x4 h0 = MFMA16(w1a[0], bf1, Z4, 0, 0, 0);
      const f32x4 h1 = MFMA16(w1a[1], bf1, Z4, 0, 0, 0);
      // relu + pack straight into layer-2 B-frag (channel-permuted L1 rows)
      const s16x8 bf2 = mk8(pkt(fmaxf(h0[0], 0.f), fmaxf(h0[1], 0.f)),
                            pkt(fmaxf(h0[2], 0.f), fmaxf(h0[3], 0.f)),
                            pkt(fmaxf(h1[0], 0.f), fmaxf(h1[1], 0.f)),
                            pkt(fmaxf(h1[2], 0.f), fmaxf(h1[3], 0.f)));
      const f32x4 Lg = MFMA16(w2a, bf2, b2v, 0, 0, 0);  // bias via C-in
      // logits (pre-scaled by log2e): lane (l15=pair, lg<2) holds h = lg*4+i
      if (lglo) {
        #pragma unroll
        for (int i = 0; i < 4; ++i) {
          const float e = exp2f(Lg[i]);  // raw v_exp_f32
          P_s[pb][lg * 4 + i][qg][kk] = (u16)(__builtin_bit_cast(unsigned, e) >> 16);
        }
      }
    }
    __syncthreads();  // P[pb] complete (sole barrier this kt; drains vfr too)

    // ---- PV + sum MFMA: heads {2wid, 2wid+1}, V from prefetched regs ----
    #pragma unroll
    for (int hh = 0; hh < 2; ++hh) {
      const int h = wid * 2 + hh;
      s16x8 pa[2];
      #pragma unroll
      for (int ks = 0; ks < 2; ++ks)
        pa[ks] = *(const s16x8*)&P_s[pb][h][l15][ks * 32 + lg * 8];
      #pragma unroll
      for (int dh = 0; dh < 2; ++dh)
        #pragma unroll
        for (int ks = 0; ks < 2; ++ks)
          acc_pv[hh][dh] = MFMA16(pa[ks], vfr[hh][dh][ks], acc_pv[hh][dh], 0, 0, 0);
      #pragma unroll
      for (int ks = 0; ks < 2; ++ks)
        acc_sum[hh] = MFMA16(pa[ks], ones, acc_sum[hh], 0, 0, 0);
    }
    // no trailing barrier: next kt writes the OTHER buffer; its barrier
    // (after next MLP) orders these reads before the buffer's next reuse.
  }

  // ---- epilogue: store bf16 partial PV and f32 partial L ----
  #pragma unroll
  for (int hh = 0; hh < 2; ++hh) {
    const int h = wid * 2 + hh;
    #pragma unroll
    for (int dh = 0; dh < 2; ++dh)
      #pragma unroll
      for (int i = 0; i < 4; ++i) {
        const int qr = lg * 4 + i;
        myPre[((size_t)(m * 1024 + q0 + qr)) * 256 + h * 32 + dh * 16 + l15] =
            f2b(acc_pv[hh][dh][i]);
      }
    if (l15 == 0) {
      #pragma unroll
      for (int i = 0; i < 4; ++i)
        myL[((size_t)(m * 1024 + q0 + lg * 4 + i)) * 8 + h] = acc_sum[hh][i];
    }
  }
}

// ---------------- output projection with 2-way partial combine -------------
__global__ __launch_bounds__(256) void outp_kernel(
    const u16* __restrict__ preP, const float* __restrict__ Lb,
    const u16* __restrict__ WoT,
    const float* __restrict__ bout, float* __restrict__ out) {
  const int n0 = blockIdx.x * 64;
  const int j0 = blockIdx.y * 64;
  const int tid = threadIdx.x;
  const int lane = tid & 63, wid = tid >> 6;
  const int l15 = lane & 15, lg = lane >> 4;
  const int wn = wid & 1, wj = wid >> 1;
  __shared__ u16 As[64][40];
  __shared__ u16 Bs[64][40];
  f32x4 acc[2][2];
  #pragma unroll
  for (int a = 0; a < 2; ++a)
    #pragma unroll
    for (int b = 0; b < 2; ++b) acc[a][b] = (f32x4){0.f, 0.f, 0.f, 0.f};

  const size_t PSTRIDE = (size_t)8192 * 256;
  const size_t LSTRIDE = (size_t)8192 * 8;

  for (int ks = 0; ks < 8; ++ks) {
    const int d0 = ks * 32;
    const int r = tid >> 2, cb = (tid & 3) * 8;
    const size_t row = (size_t)(n0 + r);
    const float Ls = Lb[row * 8 + ks] + Lb[LSTRIDE + row * 8 + ks];
    const float inv = 1.0f / Ls;
    const s16x8 p0 = *(const s16x8*)&preP[row * 256 + d0 + cb];
    const s16x8 p1 = *(const s16x8*)&preP[PSTRIDE + row * 256 + d0 + cb];
    s16x8 t;
    #pragma unroll
    for (int j = 0; j < 8; ++j)
      t[j] = (short)f2b((b2f((u16)p0[j]) + b2f((u16)p1[j])) * inv);
    *(s16x8*)&As[r][cb] = t;
    *(s16x8*)&Bs[r][cb] = *(const s16x8*)&WoT[(size_t)(j0 + r) * 256 + d0 + cb];
    __syncthreads();
    s16x8 a0 = *(const s16x8*)&As[wn * 32 + l15][lg * 8];
    s16x8 a1 = *(const s16x8*)&As[wn * 32 + 16 + l15][lg * 8];
    s16x8 b0 = *(const s16x8*)&Bs[wj * 32 + l15][lg * 8];
    s16x8 b1 = *(const s16x8*)&Bs[wj * 32 + 16 + l15][lg * 8];
    acc[0][0] = MFMA16(a0, b0, acc[0][0], 0, 0, 0);
    acc[0][1] = MFMA16(a0, b1, acc[0][1], 0, 0, 0);
    acc[1][0] = MFMA16(a1, b0, acc[1][0], 0, 0, 0);
    acc[1][1] = MFMA16(a1, b1, acc[1][1], 0, 0, 0);
    __syncthreads();
  }
  #pragma unroll
  for (int sn = 0; sn < 2; ++sn)
    #pragma unroll
    for (int sj = 0; sj < 2; ++sj)
      #pragma unroll
      for (int i = 0; i < 4; ++i) {
        int n = n0 + wn * 32 + sn * 16 + lg * 4 + i;
        int j = j0 + wj * 32 + sj * 16 + l15;
        out[(size_t)n * 256 + j] = acc[sn][sj][i] + bout[j];
      }
}

extern "C" void kernel_launch(void* const* d_in, const int* in_sizes, int n_in,
                              void* d_out, int out_size, void* d_ws, size_t ws_size,
                              hipStream_t stream) {
  const float* zq = (const float*)d_in[0];
  const float* zk = (const float*)d_in[1];
  const float* zv = (const float*)d_in[2];
  const float* xq = (const float*)d_in[3];
  const float* xkv = (const float*)d_in[4];
  const float* Wq = (const float*)d_in[5];
  const float* Wk = (const float*)d_in[6];
  const float* Wv = (const float*)d_in[7];
  const float* Wo = (const float*)d_in[8];
  const float* bout = (const float*)d_in[9];
  const float* W1 = (const float*)d_in[10];
  const float* b1 = (const float*)d_in[11];
  const float* W2 = (const float*)d_in[12];
  const float* b2 = (const float*)d_in[13];
  float* out = (float*)d_out;

  const size_t MB = (size_t)1 << 20;
  char* ws = (char*)d_ws;
  u16* qb   = (u16*)(ws + 0 * MB);
  u16* kb   = (u16*)(ws + 4 * MB);
  u16* vT   = (u16*)(ws + 8 * MB);
  u16* preP = (u16*)(ws + 12 * MB);      // 2 x 4 MB (bf16 partial PV)
  float* Lb = (float*)(ws + 20 * MB);    // 2 x 256 KB (f32 partial L)
  char* wbase = ws + 21 * MB;
  u16* WqT  = (u16*)(wbase + 0 * (128 << 10));
  u16* WkT  = (u16*)(wbase + 1 * (128 << 10));
  u16* WvT  = (u16*)(wbase + 2 * (128 << 10));
  u16* WoT  = (u16*)(wbase + 3 * (128 << 10));

  wtrans_kernel<<<dim3(4, 256), dim3(256), 0, stream>>>(Wq, Wk, Wv, Wo, WqT, WkT, WvT, WoT);
  proj_kernel<<<dim3(128, 4, 3), dim3(256), 0, stream>>>(zq, zk, zv, WqT, WkT, WvT, qb, kb, vT);
  attn_kernel<<<dim3(1024), dim3(256), 0, stream>>>(qb, kb, vT, xq, xkv, W1, b1, W2, b2, preP, Lb);
  outp_kernel<<<dim3(128, 4), dim3(256), 0, stream>>>(preP, Lb, WoT, bout, out);
  copyxq_kernel<<<dim3(64), dim3(256), 0, stream>>>(xq, out + (size_t)8 * 1024 * 256);
}